// Round 12
// baseline (249.212 us; speedup 1.0000x reference)
//
#include <hip/hip_runtime.h>

typedef unsigned long long u64;
typedef unsigned int u32;

#define N1 4096
#define N2 2048
#define NT 6144
#define CAP 4096
#define MCAP 4096
#define IMG 1280.0f
#define MATCH_IOU_T 0.8f
#define NMS_IOU_T 0.95f

// IoU with exact op-order mirroring of the reference (no FMA contraction).
__device__ __forceinline__ float iou_f(const float* a, const float* b) {
    float x1 = fmaxf(a[0], b[0]);
    float y1 = fmaxf(a[1], b[1]);
    float x2 = fminf(a[2], b[2]);
    float y2 = fminf(a[3], b[3]);
    float dx = fmaxf(__fsub_rn(x2, x1), 0.0f);
    float dy = fmaxf(__fsub_rn(y2, y1), 0.0f);
    float inter = __fmul_rn(dx, dy);
    float a1 = __fmul_rn(__fsub_rn(a[2], a[0]), __fsub_rn(a[3], a[1]));
    float a2 = __fmul_rn(__fsub_rn(b[2], b[0]), __fsub_rn(b[3], b[1]));
    float den = __fsub_rn(__fadd_rn(a1, a2), inter);
    return __fdiv_rn(inter, den);
}

// Kernel A: grid phase = match candidate pairs (4 yolo rows/block, b2
// normalized inline == old k0's exact __fdiv_rn); serial tail = LAST block
// (done-counter election, dispatch-order-independent) sorts pairs, runs the
// exact greedy walk, applies merges, emits sort keys + valid2.
__global__ void __launch_bounds__(256) kA(const float* yb, const float* ys,
                                          const int* yl, const int* fl,
                                          const float* fb, const float* fs,
                                          float* mbox, float* mscore, int* valid2,
                                          u64* keys, int* mpcount, u64* mpk,
                                          float* mpi, int* doneA) {
    __shared__ u64 pk[MCAP];            // 32 KB (last block only)
    __shared__ float pv[MCAP];          // 16 KB
    __shared__ unsigned char dec[MCAP]; //  4 KB
    __shared__ unsigned char used[N2];  //  2 KB
    __shared__ int flag_s;
    int tid = threadIdx.x;
    int base = blockIdx.x * 4;
    // ---- P1: candidate pairs ----
    for (int r = 0; r < 4; r++) {
        int i = base + r;
        float a[4];
#pragma unroll
        for (int c = 0; c < 4; c++) a[c] = __fdiv_rn(yb[i * 4 + c], IMG);
        int lab = yl[i];
        for (int j = tid; j < N2; j += 256) {
            if (fl[j] == lab) {
                float bb[4];
#pragma unroll
                for (int c = 0; c < 4; c++) bb[c] = __fdiv_rn(fb[j * 4 + c], IMG);
                float v = iou_f(a, bb);
                if (v >= MATCH_IOU_T) {
                    int pos = atomicAdd(mpcount, 1);
                    if (pos < MCAP) { mpk[pos] = (((u64)(u32)i) << 32) | (u32)j; mpi[pos] = v; }
                }
            }
        }
    }
    if (tid < 4) {
        int i = base + tid;
#pragma unroll
        for (int c = 0; c < 4; c++) mbox[i * 4 + c] = __fdiv_rn(yb[i * 4 + c], IMG);
        mscore[i] = __fmul_rn(ys[i], 0.5f);
    }
    // ---- last-block election (release: fence before counter bump) ----
    __threadfence();
    __syncthreads();
    if (tid == 0) {
        int prev = atomicAdd(doneA, 1);
        flag_s = (prev == (int)gridDim.x - 1) ? 1 : 0;
    }
    __syncthreads();
    if (!flag_s) return;
    __threadfence();   // acquire: see all other blocks' writes (cross-XCD)
    // ---- P2: exact greedy resolve (same as proven k2_match body) ----
    int np = atomicAdd(mpcount, 0);
    if (np > MCAP) np = MCAP;
    for (int t = tid; t < MCAP; t += 256) {
        pk[t] = (t < np) ? mpk[t] : ~0ULL;
        pv[t] = (t < np) ? mpi[t] : 0.0f;
        dec[t] = 0;
    }
    for (int j = tid; j < N2; j += 256) used[j] = 0;
    __syncthreads();
    if (np > 0) {
        int m = 2;
        while (m < np) m <<= 1;
        for (int k2 = 2; k2 <= m; k2 <<= 1) {
            for (int jj = k2 >> 1; jj > 0; jj >>= 1) {
                for (int idx = tid; idx < m; idx += 256) {
                    int l = idx ^ jj;
                    if (l > idx) {
                        u64 A = pk[idx], B = pk[l];
                        bool up = ((idx & k2) == 0);
                        if (up ? (A > B) : (A < B)) {
                            pk[idx] = B; pk[l] = A;
                            float fA = pv[idx]; pv[idx] = pv[l]; pv[l] = fA;
                        }
                    }
                }
                __syncthreads();
            }
        }
        if (tid == 0) {
            int cur_i = -1, best_p = -1, best_j = -1;
            float best_v = -1.0f;
            for (int p = 0; p < np; p++) {
                u64 pr = pk[p];
                int i = (int)(pr >> 32);
                int j = (int)(pr & 0xffffffffu);
                if (i != cur_i) {
                    if (best_p >= 0) { dec[best_p] = 1; used[best_j] = 1; }
                    cur_i = i; best_p = -1; best_j = -1; best_v = -1.0f;
                }
                if (!used[j]) {
                    float v = pv[p];
                    if (v > best_v) { best_v = v; best_p = p; best_j = j; }
                }
            }
            if (best_p >= 0) { dec[best_p] = 1; used[best_j] = 1; }
        }
        __syncthreads();
        for (int p = tid; p < np; p += 256) {
            if (dec[p]) {
                u64 pr = pk[p];
                int i = (int)(pr >> 32);
                int j = (int)(pr & 0xffffffffu);
                float s2 = __fmul_rn(fs[j], 0.5f);
                float sc0 = mscore[i];
                float tot = __fadd_rn(sc0, s2);
#pragma unroll
                for (int cc = 0; cc < 4; cc++) {
                    float b2v = __fdiv_rn(fb[j * 4 + cc], IMG);
                    float merged = __fdiv_rn(
                        __fadd_rn(__fmul_rn(mbox[i * 4 + cc], sc0),
                                  __fmul_rn(b2v, s2)), tot);
                    mbox[i * 4 + cc] = merged;
                }
                mscore[i] = tot;
            }
        }
        __syncthreads();   // global writes visible block-wide for keys phase
    }
    // keys: stable argsort(-where(valid,s,-1)) == ascending composite sort
    for (int idx = tid; idx < NT; idx += 256) {
        float sc; int val;
        if (idx < N1) { sc = mscore[idx]; val = 1; }
        else          { sc = __fmul_rn(fs[idx - N1], 0.5f); val = used[idx - N1] ? 0 : 1; }
        float f = val ? sc : -1.0f;
        u32 u = __float_as_uint(f);
        u32 asc = (u >> 31) ? ~u : (u | 0x80000000u);
        keys[idx] = (((u64)(~asc)) << 32) | (u32)idx;
    }
    for (int j = tid; j < N2; j += 256) valid2[j] = used[j] ? 0 : 1;
}

// Kernel B: rank-count (LDS-staged keys, 16 rows/block) + direct gather
// scatter (ranks unique -> disjoint writes). b2/s2 normalized inline.
__global__ void __launch_bounds__(256) kB(const u64* keys, const float* mbox,
                                          const float* mscore, const float* fb,
                                          const float* fs, const int* valid2,
                                          const int* yl, const int* fl,
                                          float* sboxn, int* slab, int* svalid,
                                          float* out) {
    __shared__ u64 ks[NT];     // 48 KB
    __shared__ int cnts[16];
    int tid = threadIdx.x;
    for (int t = tid; t < NT; t += 256) ks[t] = keys[t];
    if (tid < 16) cnts[tid] = 0;
    __syncthreads();
    int i0 = blockIdx.x * 16;
    u64 myk[16];
#pragma unroll
    for (int g = 0; g < 16; g++) myk[g] = ks[i0 + g];
    int local[16];
#pragma unroll
    for (int g = 0; g < 16; g++) local[g] = 0;
    for (int j = tid; j < NT; j += 256) {
        u64 kj = ks[j];
#pragma unroll
        for (int g = 0; g < 16; g++) local[g] += (kj < myk[g]) ? 1 : 0;
    }
#pragma unroll
    for (int g = 0; g < 16; g++) {
        int v = local[g];
#pragma unroll
        for (int s = 32; s > 0; s >>= 1) v += __shfl_down(v, s, 64);
        if ((tid & 63) == 0) atomicAdd(&cnts[g], v);
    }
    __syncthreads();
    if (tid < 16) {
        int i = i0 + tid;
        int r = cnts[tid];
        float b[4]; int lab; float sc; int val;
        if (i < N1) {
#pragma unroll
            for (int c = 0; c < 4; c++) b[c] = mbox[i * 4 + c];
            lab = yl[i]; sc = mscore[i]; val = 1;
        } else {
            int j = i - N1;
#pragma unroll
            for (int c = 0; c < 4; c++) b[c] = __fdiv_rn(fb[j * 4 + c], IMG);
            lab = fl[j]; sc = __fmul_rn(fs[j], 0.5f); val = valid2[j];
        }
#pragma unroll
        for (int c = 0; c < 4; c++) {
            sboxn[r * 4 + c] = b[c];
            out[r * 4 + c] = __fmul_rn(b[c], IMG);
        }
        slab[r] = lab; svalid[r] = val;
        out[24576 + r] = (lab == 0) ? 2.0f : 1.0f;   // label_map[clip(l,0,1)]
        out[24576 + NT + r] = sc;                     // sorted scores
    }
}

// Kernel C: grid phase = NMS candidate pairs (4 sorted rows/block); serial
// tail = LAST block sorts pairs + exact sequential suppression + keep mask.
__global__ void __launch_bounds__(256) kC(const float* sboxn, const int* slab,
                                          const int* svalid, int* pcount,
                                          u64* pairs, int* doneC, float* out) {
    __shared__ u64 pl[CAP];            // 32 KB (last block only)
    __shared__ unsigned char sup[NT];  //  6 KB
    __shared__ int flag_s;
    int tid = threadIdx.x;
    int base = blockIdx.x * 4;
    for (int r = 0; r < 4; r++) {
        int i = base + r;
        float a[4] = {sboxn[i * 4], sboxn[i * 4 + 1], sboxn[i * 4 + 2], sboxn[i * 4 + 3]};
        int lab = slab[i];
        for (int j = i + 1 + tid; j < NT; j += 256) {
            if (slab[j] == lab) {
                float bb[4] = {sboxn[j * 4], sboxn[j * 4 + 1], sboxn[j * 4 + 2], sboxn[j * 4 + 3]};
                if (iou_f(a, bb) >= NMS_IOU_T) {
                    int pos = atomicAdd(pcount, 1);
                    if (pos < CAP) pairs[pos] = (((u64)(u32)i) << 32) | (u32)j;
                }
            }
        }
    }
    __threadfence();
    __syncthreads();
    if (tid == 0) {
        int prev = atomicAdd(doneC, 1);
        flag_s = (prev == (int)gridDim.x - 1) ? 1 : 0;
    }
    __syncthreads();
    if (!flag_s) return;
    __threadfence();
    int np = atomicAdd(pcount, 0);
    if (np > CAP) np = CAP;
    int m = 2;
    while (m < np) m <<= 1;   // block-uniform
    for (int t = tid; t < m; t += 256) pl[t] = (t < np) ? pairs[t] : ~0ULL;
    for (int k = tid; k < NT; k += 256) sup[k] = svalid[k] ? 0 : 1;
    __syncthreads();
    if (np > 0) {
        for (int k2 = 2; k2 <= m; k2 <<= 1) {
            for (int jj = k2 >> 1; jj > 0; jj >>= 1) {
                for (int idx = tid; idx < m; idx += 256) {
                    int l = idx ^ jj;
                    if (l > idx) {
                        u64 A = pl[idx], B = pl[l];
                        bool up = ((idx & k2) == 0);
                        if (up ? (A > B) : (A < B)) { pl[idx] = B; pl[l] = A; }
                    }
                }
                __syncthreads();
            }
        }
        if (tid == 0) {
            for (int p = 0; p < np; p++) {
                u64 pr = pl[p];
                int i = (int)(pr >> 32);
                int j = (int)(pr & 0xffffffffu);
                if (!sup[i]) sup[j] = 1;
            }
        }
        __syncthreads();
    }
    for (int k = tid; k < NT; k += 256) out[24576 + 2 * NT + k] = sup[k] ? 0.0f : 1.0f;
}

extern "C" void kernel_launch(void* const* d_in, const int* in_sizes, int n_in,
                              void* d_out, int out_size, void* d_ws, size_t ws_size,
                              hipStream_t stream) {
    const float* yb = (const float*)d_in[0];
    const float* ys = (const float*)d_in[1];
    const int*   yl = (const int*)d_in[2];
    const float* fb = (const float*)d_in[3];
    const float* fs = (const float*)d_in[4];
    const int*   fl = (const int*)d_in[5];
    float* out = (float*)d_out;
    char* ws = (char*)d_ws;

    float* mbox    = (float*)(ws);            // 4096*4 f = 65536 B
    float* mscore  = (float*)(ws + 65536);    // 4096 f   = 16384 B
    int*   valid2  = (int*)  (ws + 81920);    // 2048 i   =  8192 B
    u64*   keys    = (u64*)  (ws + 90112);    // 6144 u64 = 49152 B
    float* sboxn   = (float*)(ws + 139264);   // 6144*4 f = 98304 B
    int*   slab    = (int*)  (ws + 237568);   // 6144 i   = 24576 B
    int*   svalid  = (int*)  (ws + 262144);   // 6144 i   = 24576 B
    int*   cnt     = (int*)  (ws + 286720);   // 4 ints: pcount,mpcount,doneA,doneC
    u64*   mpk     = (u64*)  (ws + 286736);   // 4096 u64 = 32768 B
    float* mpi     = (float*)(ws + 319504);   // 4096 f   = 16384 B
    u64*   pairs   = (u64*)  (ws + 335888);   // 4096 u64 = 32768 B (end ~360 KB)
    int* pcount  = cnt + 0;
    int* mpcount = cnt + 1;
    int* doneA   = cnt + 2;
    int* doneC   = cnt + 3;

    hipMemsetAsync(cnt, 0, 16, stream);
    hipLaunchKernelGGL(kA, dim3(N1 / 4), dim3(256), 0, stream,
                       yb, ys, yl, fl, fb, fs, mbox, mscore, valid2, keys,
                       mpcount, mpk, mpi, doneA);
    hipLaunchKernelGGL(kB, dim3(NT / 16), dim3(256), 0, stream,
                       keys, mbox, mscore, fb, fs, valid2, yl, fl,
                       sboxn, slab, svalid, out);
    hipLaunchKernelGGL(kC, dim3(NT / 4), dim3(256), 0, stream,
                       sboxn, slab, svalid, pcount, pairs, doneC, out);
}

// Round 13
// 83.254 us; speedup vs baseline: 2.9934x; 2.9934x over previous
//
#include <hip/hip_runtime.h>

typedef unsigned long long u64;
typedef unsigned int u32;

#define N1 4096
#define N2 2048
#define NT 6144
#define CAP 4096
#define MCAP 4096
#define IMG 1280.0f
#define MATCH_IOU_T 0.8f
#define NMS_IOU_T 0.95f

// IoU with exact op-order mirroring of the reference (no FMA contraction).
__device__ __forceinline__ float iou_f(const float* a, const float* b) {
    float x1 = fmaxf(a[0], b[0]);
    float y1 = fmaxf(a[1], b[1]);
    float x2 = fminf(a[2], b[2]);
    float y2 = fminf(a[3], b[3]);
    float dx = fmaxf(__fsub_rn(x2, x1), 0.0f);
    float dy = fmaxf(__fsub_rn(y2, y1), 0.0f);
    float inter = __fmul_rn(dx, dy);
    float a1 = __fmul_rn(__fsub_rn(a[2], a[0]), __fsub_rn(a[3], a[1]));
    float a2 = __fmul_rn(__fsub_rn(b[2], b[0]), __fsub_rn(b[3], b[1]));
    float den = __fsub_rn(__fadd_rn(a1, a2), inter);
    return __fdiv_rn(inter, den);
}

// K1: ONE yolo row per block (wide grid = max latency hiding; r10 showed
// 4-rows/block under-occupies). Emit all candidate pairs (same label,
// unmasked IoU >= 0.8) with exact IoU; frcnn boxes normalized inline
// (bit-identical to the old k0 precompute). tid0 writes default mbox/mscore.
__global__ void __launch_bounds__(256) k1_pairs(const float* yb, const float* ys,
                                                const int* yl, const int* fl,
                                                const float* fb, float* mbox,
                                                float* mscore, int* mpcount,
                                                u64* mpk, float* mpi) {
    int i = blockIdx.x;
    int tid = threadIdx.x;
    float a[4];
#pragma unroll
    for (int c = 0; c < 4; c++) a[c] = __fdiv_rn(yb[i * 4 + c], IMG);
    int lab = yl[i];
    for (int j = tid; j < N2; j += 256) {
        if (fl[j] == lab) {
            float bb[4];
#pragma unroll
            for (int c = 0; c < 4; c++) bb[c] = __fdiv_rn(fb[j * 4 + c], IMG);
            float v = iou_f(a, bb);
            if (v >= MATCH_IOU_T) {
                int pos = atomicAdd(mpcount, 1);
                if (pos < MCAP) { mpk[pos] = (((u64)(u32)i) << 32) | (u32)j; mpi[pos] = v; }
            }
        }
    }
    if (tid == 0) {
#pragma unroll
        for (int c = 0; c < 4; c++) mbox[i * 4 + c] = a[c];
        mscore[i] = __fmul_rn(ys[i], 0.5f);
    }
}

// K2: single block. Bitonic-sort pairs by (i<<32)|j (restores determinism,
// i-groups with j-ascending tie-break == argmax semantics); thread-0 greedy
// walk; parallel apply (disjoint writes); fused keys phase + valid2.
__global__ void __launch_bounds__(256) k2_match(const float* fb, const float* fs,
                                                const int* mpcount, const u64* mpk,
                                                const float* mpi, float* mbox,
                                                float* mscore, int* valid2, u64* keys) {
    __shared__ u64 pk[MCAP];            // 32 KB
    __shared__ float pv[MCAP];          // 16 KB
    __shared__ unsigned char dec[MCAP]; //  4 KB
    __shared__ unsigned char used[N2];  //  2 KB
    int tid = threadIdx.x;
    int np = *mpcount;
    if (np > MCAP) np = MCAP;
    for (int t = tid; t < MCAP; t += 256) {
        pk[t] = (t < np) ? mpk[t] : ~0ULL;
        pv[t] = (t < np) ? mpi[t] : 0.0f;
        dec[t] = 0;
    }
    for (int j = tid; j < N2; j += 256) used[j] = 0;
    __syncthreads();
    if (np > 0) {
        int m = 2;
        while (m < np) m <<= 1;
        for (int k2 = 2; k2 <= m; k2 <<= 1) {
            for (int jj = k2 >> 1; jj > 0; jj >>= 1) {
                for (int idx = tid; idx < m; idx += 256) {
                    int l = idx ^ jj;
                    if (l > idx) {
                        u64 A = pk[idx], B = pk[l];
                        bool up = ((idx & k2) == 0);
                        if (up ? (A > B) : (A < B)) {
                            pk[idx] = B; pk[l] = A;
                            float fA = pv[idx]; pv[idx] = pv[l]; pv[l] = fA;
                        }
                    }
                }
                __syncthreads();
            }
        }
        if (tid == 0) {
            int cur_i = -1, best_p = -1, best_j = -1;
            float best_v = -1.0f;
            for (int p = 0; p < np; p++) {
                u64 pr = pk[p];
                int i = (int)(pr >> 32);
                int j = (int)(pr & 0xffffffffu);
                if (i != cur_i) {
                    if (best_p >= 0) { dec[best_p] = 1; used[best_j] = 1; }
                    cur_i = i; best_p = -1; best_j = -1; best_v = -1.0f;
                }
                if (!used[j]) {
                    float v = pv[p];
                    if (v > best_v) { best_v = v; best_p = p; best_j = j; }
                }
            }
            if (best_p >= 0) { dec[best_p] = 1; used[best_j] = 1; }
        }
        __syncthreads();
        for (int p = tid; p < np; p += 256) {
            if (dec[p]) {
                u64 pr = pk[p];
                int i = (int)(pr >> 32);
                int j = (int)(pr & 0xffffffffu);
                float s2 = __fmul_rn(fs[j], 0.5f);
                float sc0 = mscore[i];
                float tot = __fadd_rn(sc0, s2);
#pragma unroll
                for (int cc = 0; cc < 4; cc++) {
                    float b2v = __fdiv_rn(fb[j * 4 + cc], IMG);
                    float merged = __fdiv_rn(
                        __fadd_rn(__fmul_rn(mbox[i * 4 + cc], sc0),
                                  __fmul_rn(b2v, s2)), tot);
                    mbox[i * 4 + cc] = merged;
                }
                mscore[i] = tot;
            }
        }
        __syncthreads();   // apply's global writes visible block-wide
    }
    // fused keys: stable argsort(-where(valid,s,-1)) == ascending composite
    for (int idx = tid; idx < NT; idx += 256) {
        float sc; int val;
        if (idx < N1) { sc = mscore[idx]; val = 1; }
        else          { sc = __fmul_rn(fs[idx - N1], 0.5f); val = used[idx - N1] ? 0 : 1; }
        float f = val ? sc : -1.0f;
        u32 u = __float_as_uint(f);
        u32 asc = (u >> 31) ? ~u : (u | 0x80000000u);
        keys[idx] = (((u64)(~asc)) << 32) | (u32)idx;
    }
    for (int j = tid; j < N2; j += 256) valid2[j] = used[j] ? 0 : 1;
}

// K4: rank-count (LDS-staged keys, 384 blocks x 16 rows — grid unchanged
// from the proven r7 k4) + fused direct gather (ranks unique -> disjoint).
__global__ void __launch_bounds__(256) k4_rank(const u64* keys, const float* mbox,
                                               const float* mscore, const float* fb,
                                               const float* fs, const int* valid2,
                                               const int* yl, const int* fl,
                                               float* sboxn, int* slab, int* svalid,
                                               float* out) {
    __shared__ u64 ks[NT];     // 48 KB
    __shared__ int cnts[16];
    int tid = threadIdx.x;
    for (int t = tid; t < NT; t += 256) ks[t] = keys[t];
    if (tid < 16) cnts[tid] = 0;
    __syncthreads();
    int i0 = blockIdx.x * 16;
    u64 myk[16];
#pragma unroll
    for (int g = 0; g < 16; g++) myk[g] = ks[i0 + g];
    int local[16];
#pragma unroll
    for (int g = 0; g < 16; g++) local[g] = 0;
    for (int j = tid; j < NT; j += 256) {
        u64 kj = ks[j];
#pragma unroll
        for (int g = 0; g < 16; g++) local[g] += (kj < myk[g]) ? 1 : 0;
    }
#pragma unroll
    for (int g = 0; g < 16; g++) {
        int v = local[g];
#pragma unroll
        for (int s = 32; s > 0; s >>= 1) v += __shfl_down(v, s, 64);
        if ((tid & 63) == 0) atomicAdd(&cnts[g], v);
    }
    __syncthreads();
    if (tid < 16) {
        int i = i0 + tid;
        int r = cnts[tid];
        float b[4]; int lab; float sc; int val;
        if (i < N1) {
#pragma unroll
            for (int c = 0; c < 4; c++) b[c] = mbox[i * 4 + c];
            lab = yl[i]; sc = mscore[i]; val = 1;
        } else {
            int j = i - N1;
#pragma unroll
            for (int c = 0; c < 4; c++) b[c] = __fdiv_rn(fb[j * 4 + c], IMG);
            lab = fl[j]; sc = __fmul_rn(fs[j], 0.5f); val = valid2[j];
        }
#pragma unroll
        for (int c = 0; c < 4; c++) {
            sboxn[r * 4 + c] = b[c];
            out[r * 4 + c] = __fmul_rn(b[c], IMG);
        }
        slab[r] = lab; svalid[r] = val;
        out[24576 + r] = (lab == 0) ? 2.0f : 1.0f;   // label_map[clip(l,0,1)]
        out[24576 + NT + r] = sc;                     // sorted scores
    }
}

// K6: ONE sorted row per block (wide grid). NMS candidate pairs
// (i<j, same label, IoU >= 0.95) -> atomic append.
__global__ void __launch_bounds__(256) k6_pairs(const float* sboxn, const int* slab,
                                                int* pcount, u64* pairs) {
    int i = blockIdx.x;
    int tid = threadIdx.x;
    float a[4] = {sboxn[i * 4], sboxn[i * 4 + 1], sboxn[i * 4 + 2], sboxn[i * 4 + 3]};
    int lab = slab[i];
    for (int j = i + 1 + tid; j < NT; j += 256) {
        if (slab[j] == lab) {
            float bb[4] = {sboxn[j * 4], sboxn[j * 4 + 1], sboxn[j * 4 + 2], sboxn[j * 4 + 3]};
            if (iou_f(a, bb) >= NMS_IOU_T) {
                int pos = atomicAdd(pcount, 1);
                if (pos < CAP) pairs[pos] = (((u64)(u32)i) << 32) | (u32)j;
            }
        }
    }
}

// K7: single block. Sort pairs (determinism after atomic append), exact
// sequential suppression, keep mask. Runtime-sized bitonic.
__global__ void __launch_bounds__(256) k7_resolve(const int* pcount, const u64* pairs,
                                                  const int* svalid, float* out) {
    __shared__ u64 pl[CAP];
    __shared__ unsigned char sup[NT];
    int tid = threadIdx.x;
    int np = *pcount;
    if (np > CAP) np = CAP;
    int m = 2;
    while (m < np) m <<= 1;   // block-uniform
    for (int t = tid; t < m; t += 256) pl[t] = (t < np) ? pairs[t] : ~0ULL;
    for (int k = tid; k < NT; k += 256) sup[k] = svalid[k] ? 0 : 1;
    __syncthreads();
    if (np > 0) {
        for (int k2 = 2; k2 <= m; k2 <<= 1) {
            for (int jj = k2 >> 1; jj > 0; jj >>= 1) {
                for (int idx = tid; idx < m; idx += 256) {
                    int l = idx ^ jj;
                    if (l > idx) {
                        u64 A = pl[idx], B = pl[l];
                        bool up = ((idx & k2) == 0);
                        if (up ? (A > B) : (A < B)) { pl[idx] = B; pl[l] = A; }
                    }
                }
                __syncthreads();
            }
        }
        if (tid == 0) {
            for (int p = 0; p < np; p++) {
                u64 pr = pl[p];
                int i = (int)(pr >> 32);
                int j = (int)(pr & 0xffffffffu);
                if (!sup[i]) sup[j] = 1;
            }
        }
        __syncthreads();
    }
    for (int k = tid; k < NT; k += 256) out[24576 + 2 * NT + k] = sup[k] ? 0.0f : 1.0f;
}

extern "C" void kernel_launch(void* const* d_in, const int* in_sizes, int n_in,
                              void* d_out, int out_size, void* d_ws, size_t ws_size,
                              hipStream_t stream) {
    const float* yb = (const float*)d_in[0];
    const float* ys = (const float*)d_in[1];
    const int*   yl = (const int*)d_in[2];
    const float* fb = (const float*)d_in[3];
    const float* fs = (const float*)d_in[4];
    const int*   fl = (const int*)d_in[5];
    float* out = (float*)d_out;
    char* ws = (char*)d_ws;

    float* mbox    = (float*)(ws);            // 4096*4 f = 65536 B
    float* mscore  = (float*)(ws + 65536);    // 4096 f   = 16384 B
    int*   valid2  = (int*)  (ws + 81920);    // 2048 i   =  8192 B
    u64*   keys    = (u64*)  (ws + 90112);    // 6144 u64 = 49152 B
    float* sboxn   = (float*)(ws + 139264);   // 6144*4 f = 98304 B
    int*   slab    = (int*)  (ws + 237568);   // 6144 i   = 24576 B
    int*   svalid  = (int*)  (ws + 262144);   // 6144 i   = 24576 B
    int*   cnt     = (int*)  (ws + 286720);   // 2 ints: pcount, mpcount
    u64*   mpk     = (u64*)  (ws + 286736);   // 4096 u64 = 32768 B
    float* mpi     = (float*)(ws + 319504);   // 4096 f   = 16384 B
    u64*   pairs   = (u64*)  (ws + 335888);   // 4096 u64 = 32768 B (end ~360 KB)
    int* pcount  = cnt + 0;
    int* mpcount = cnt + 1;

    hipMemsetAsync(cnt, 0, 8, stream);
    hipLaunchKernelGGL(k1_pairs, dim3(N1),     dim3(256), 0, stream,
                       yb, ys, yl, fl, fb, mbox, mscore, mpcount, mpk, mpi);
    hipLaunchKernelGGL(k2_match, dim3(1),      dim3(256), 0, stream,
                       fb, fs, mpcount, mpk, mpi, mbox, mscore, valid2, keys);
    hipLaunchKernelGGL(k4_rank,  dim3(NT/16),  dim3(256), 0, stream,
                       keys, mbox, mscore, fb, fs, valid2, yl, fl,
                       sboxn, slab, svalid, out);
    hipLaunchKernelGGL(k6_pairs, dim3(NT),     dim3(256), 0, stream,
                       sboxn, slab, pcount, pairs);
    hipLaunchKernelGGL(k7_resolve, dim3(1),    dim3(256), 0, stream,
                       pcount, pairs, svalid, out);
}